// Round 1
// baseline (418.645 us; speedup 1.0000x reference)
//
#include <hip/hip_runtime.h>

// CommAttention: B=256, NB=16, HID=512, NH=8, KD=64.
// Phase A: qkv grouped GEMM (bf16 MFMA), Phase B: 16x16 attention + mask,
// Phase C: output grouped GEMM with split-K=2 + f32 atomics.

typedef short s16x4 __attribute__((ext_vector_type(4)));
typedef short s16x8 __attribute__((ext_vector_type(8)));
typedef float f32x4 __attribute__((ext_vector_type(4)));

__device__ __forceinline__ unsigned short f2bf(float f) {
  unsigned int u = __builtin_bit_cast(unsigned int, f);
  u += 0x7fffu + ((u >> 16) & 1u);   // round-to-nearest-even
  return (unsigned short)(u >> 16);
}
__device__ __forceinline__ float bf2f(unsigned short s) {
  unsigned int u = ((unsigned int)s) << 16;
  return __builtin_bit_cast(float, u);
}

// ---------------------------------------------------------------------------
// Phase A: fused grouped QKV projection.
// grid (80, 16): 2 m-blocks x 40 col-blocks (4 q + 4 k + 32 v), group = blockIdx.y
// A = h[:, g, :]: 256x512 fp32, row stride 8192. Tiles 128x128, BK=32.
// ---------------------------------------------------------------------------
__global__ __launch_bounds__(256) void qkv_gemm(
    const float* __restrict__ h, const float* __restrict__ Wq,
    const float* __restrict__ Wk, const float* __restrict__ Wv,
    unsigned short* __restrict__ qo, unsigned short* __restrict__ ko,
    unsigned short* __restrict__ vo)
{
  const int g    = blockIdx.y;
  const int m0   = (blockIdx.x / 40) * 128;
  const int n0   = (blockIdx.x % 40) * 128;
  const int tid  = threadIdx.x;
  const int lane = tid & 63;
  const int wave = tid >> 6;
  const int wm   = (wave >> 1) * 64;
  const int wn   = (wave & 1) * 64;

  const float* W; unsigned short* out; int obase, oldc, wN, c0;
  if (n0 < 512)       { W = Wq + (size_t)g * 262144;  out = qo; obase = g * 512;  oldc = 8192;  wN = 512;  c0 = n0; }
  else if (n0 < 1024) { W = Wk + (size_t)g * 262144;  out = ko; obase = g * 512;  oldc = 8192;  wN = 512;  c0 = n0 - 512; }
  else                { W = Wv + (size_t)g * 2097152; out = vo; obase = g * 4096; oldc = 65536; wN = 4096; c0 = n0 - 1024; }

  const float* A = h + (size_t)g * 512 + (size_t)m0 * 8192;

  __shared__ unsigned short As[128][32];   // [m][k]
  __shared__ unsigned short Bs[128][36];   // [n][k], padded stride 36 (72B)

  f32x4 acc[4][4];
  #pragma unroll
  for (int i = 0; i < 4; i++)
    #pragma unroll
    for (int j = 0; j < 4; j++) acc[i][j] = (f32x4){0.f, 0.f, 0.f, 0.f};

  const int fr = lane & 15, fq = lane >> 4;

  for (int k0 = 0; k0 < 512; k0 += 32) {
    __syncthreads();
    // stage A: 128x32 fp32 -> bf16 LDS
    #pragma unroll
    for (int p = 0; p < 4; p++) {
      int idx = p * 256 + tid;
      int row = idx >> 3, kc = idx & 7;
      float4 av = *reinterpret_cast<const float4*>(A + (size_t)row * 8192 + k0 + kc * 4);
      s16x4 st = { (short)f2bf(av.x), (short)f2bf(av.y), (short)f2bf(av.z), (short)f2bf(av.w) };
      *reinterpret_cast<s16x4*>(&As[row][kc * 4]) = st;
    }
    // stage B transposed: column loads of W (coalesced across lanes in n)
    #pragma unroll
    for (int p = 0; p < 4; p++) {
      int idx = p * 256 + tid;
      int n = idx & 127, kc = idx >> 7;
      const float* wp = W + (size_t)(k0 + kc * 4) * wN + c0 + n;
      float w0 = wp[0], w1 = wp[wN], w2 = wp[2 * wN], w3 = wp[3 * wN];
      s16x4 st = { (short)f2bf(w0), (short)f2bf(w1), (short)f2bf(w2), (short)f2bf(w3) };
      *reinterpret_cast<s16x4*>(&Bs[n][kc * 4]) = st;
    }
    __syncthreads();
    s16x8 af[4], bfr[4];
    #pragma unroll
    for (int mi = 0; mi < 4; mi++)
      af[mi] = *reinterpret_cast<const s16x8*>(&As[wm + mi * 16 + fr][fq * 8]);
    #pragma unroll
    for (int ni = 0; ni < 4; ni++) {
      const s16x4* bp = reinterpret_cast<const s16x4*>(&Bs[wn + ni * 16 + fr][fq * 8]);
      s16x4 lo = bp[0], hi = bp[1];
      bfr[ni] = __builtin_shufflevector(lo, hi, 0, 1, 2, 3, 4, 5, 6, 7);
    }
    #pragma unroll
    for (int mi = 0; mi < 4; mi++)
      #pragma unroll
      for (int ni = 0; ni < 4; ni++)
        acc[mi][ni] = __builtin_amdgcn_mfma_f32_16x16x32_bf16(af[mi], bfr[ni], acc[mi][ni], 0, 0, 0);
  }

  #pragma unroll
  for (int mi = 0; mi < 4; mi++)
    #pragma unroll
    for (int ni = 0; ni < 4; ni++)
      #pragma unroll
      for (int r = 0; r < 4; r++) {
        int row = m0 + wm + mi * 16 + fq * 4 + r;
        int col = c0 + wn + ni * 16 + fr;
        out[(size_t)obase + (size_t)row * oldc + col] = f2bf(acc[mi][ni][r]);
      }
}

// ---------------------------------------------------------------------------
// Phase B: per-(b,h) attention. 16 queries x 16 keys, softmax over 16,
// post-softmax row mask by mask[b,q], ctx = probs @ v (16x512).
// grid 2048, block 256.
// ---------------------------------------------------------------------------
__global__ __launch_bounds__(256) void attn_kernel(
    const unsigned short* __restrict__ q, const unsigned short* __restrict__ k,
    const unsigned short* __restrict__ v, const int* __restrict__ mask,
    unsigned short* __restrict__ ctx)
{
  const int b  = blockIdx.x >> 3;
  const int hh = blockIdx.x & 7;
  const int tid = threadIdx.x;

  __shared__ float qs[16][65];
  __shared__ float ks[16][65];
  __shared__ float sc[16][16];

  #pragma unroll
  for (int p = 0; p < 4; p++) {
    int idx = p * 256 + tid;
    int n = idx >> 6, d = idx & 63;
    size_t gi = ((size_t)(b * 16 + n) << 9) + (hh << 6) + d;
    qs[n][d] = bf2f(q[gi]);
    ks[n][d] = bf2f(k[gi]);
  }
  __syncthreads();
  {
    int qi = tid >> 4, ki = tid & 15;
    float s = 0.f;
    #pragma unroll
    for (int j = 0; j < 64; j++) s += qs[qi][j] * ks[ki][j];
    sc[qi][ki] = s * 0.125f;   // 1/sqrt(64)
  }
  __syncthreads();
  if (tid < 16) {
    float m = sc[tid][0];
    #pragma unroll
    for (int j = 1; j < 16; j++) m = fmaxf(m, sc[tid][j]);
    float ev[16], sum = 0.f;
    #pragma unroll
    for (int j = 0; j < 16; j++) { ev[j] = __expf(sc[tid][j] - m); sum += ev[j]; }
    float scale = (mask[b * 16 + tid] != 0) ? (1.f / sum) : 0.f;
    #pragma unroll
    for (int j = 0; j < 16; j++) sc[tid][j] = ev[j] * scale;
  }
  __syncthreads();
  #pragma unroll
  for (int p = 0; p < 2; p++) {
    int e0 = p * 256 + tid;
    float vv[16];
    #pragma unroll
    for (int kk = 0; kk < 16; kk++)
      vv[kk] = bf2f(v[((size_t)(b * 16 + kk) << 12) + (hh << 9) + e0]);
    #pragma unroll
    for (int qi = 0; qi < 16; qi++) {
      float s = 0.f;
      #pragma unroll
      for (int kk = 0; kk < 16; kk++) s += sc[qi][kk] * vv[kk];
      ctx[((size_t)(b * 16 + qi) << 12) + (hh << 9) + e0] = f2bf(s);
    }
  }
}

// ---------------------------------------------------------------------------
// Phase C: out = ctx @ Wo[g], grouped, K=4096, split-K=2 with f32 atomics.
// grid (16, 16): bx = sk*8 + mblk*4 + nblk. Tiles 128x128.
// ---------------------------------------------------------------------------
__global__ __launch_bounds__(256) void out_gemm(
    const unsigned short* __restrict__ ctxp, const float* __restrict__ Wo,
    float* __restrict__ outp)
{
  const int g    = blockIdx.y;
  const int bx   = blockIdx.x;
  const int sk   = bx >> 3;
  const int m0   = ((bx >> 2) & 1) * 128;
  const int n0   = (bx & 3) * 128;
  const int tid  = threadIdx.x;
  const int lane = tid & 63;
  const int wave = tid >> 6;
  const int wm   = (wave >> 1) * 64;
  const int wn   = (wave & 1) * 64;

  const unsigned short* A = ctxp + (size_t)g * 4096 + (size_t)m0 * 65536;
  const float* W = Wo + (size_t)g * 2097152;

  __shared__ unsigned short As[128][32];
  __shared__ unsigned short Bs[128][36];

  f32x4 acc[4][4];
  #pragma unroll
  for (int i = 0; i < 4; i++)
    #pragma unroll
    for (int j = 0; j < 4; j++) acc[i][j] = (f32x4){0.f, 0.f, 0.f, 0.f};

  const int fr = lane & 15, fq = lane >> 4;
  const int kend = sk * 2048 + 2048;

  for (int k0 = sk * 2048; k0 < kend; k0 += 32) {
    __syncthreads();
    #pragma unroll
    for (int p = 0; p < 4; p++) {
      int idx = p * 256 + tid;
      int row = idx >> 3, kc = idx & 7;
      s16x4 av = *reinterpret_cast<const s16x4*>(A + (size_t)row * 65536 + k0 + kc * 4);
      *reinterpret_cast<s16x4*>(&As[row][kc * 4]) = av;
    }
    #pragma unroll
    for (int p = 0; p < 4; p++) {
      int idx = p * 256 + tid;
      int n = idx & 127, kc = idx >> 7;
      const float* wp = W + (size_t)(k0 + kc * 4) * 512 + n0 + n;
      float w0 = wp[0], w1 = wp[512], w2 = wp[1024], w3 = wp[1536];
      s16x4 st = { (short)f2bf(w0), (short)f2bf(w1), (short)f2bf(w2), (short)f2bf(w3) };
      *reinterpret_cast<s16x4*>(&Bs[n][kc * 4]) = st;
    }
    __syncthreads();
    s16x8 af[4], bfr[4];
    #pragma unroll
    for (int mi = 0; mi < 4; mi++)
      af[mi] = *reinterpret_cast<const s16x8*>(&As[wm + mi * 16 + fr][fq * 8]);
    #pragma unroll
    for (int ni = 0; ni < 4; ni++) {
      const s16x4* bp = reinterpret_cast<const s16x4*>(&Bs[wn + ni * 16 + fr][fq * 8]);
      s16x4 lo = bp[0], hi = bp[1];
      bfr[ni] = __builtin_shufflevector(lo, hi, 0, 1, 2, 3, 4, 5, 6, 7);
    }
    #pragma unroll
    for (int mi = 0; mi < 4; mi++)
      #pragma unroll
      for (int ni = 0; ni < 4; ni++)
        acc[mi][ni] = __builtin_amdgcn_mfma_f32_16x16x32_bf16(af[mi], bfr[ni], acc[mi][ni], 0, 0, 0);
  }

  float* og = outp + (size_t)g * 512;
  #pragma unroll
  for (int mi = 0; mi < 4; mi++)
    #pragma unroll
    for (int ni = 0; ni < 4; ni++)
      #pragma unroll
      for (int r = 0; r < 4; r++) {
        int row = m0 + wm + mi * 16 + fq * 4 + r;
        int col = n0 + wn + ni * 16 + fr;
        atomicAdd(&og[(size_t)row * 8192 + col], acc[mi][ni][r]);
      }
}

// ---------------------------------------------------------------------------
extern "C" void kernel_launch(void* const* d_in, const int* in_sizes, int n_in,
                              void* d_out, int out_size, void* d_ws, size_t ws_size,
                              hipStream_t stream) {
  const float* h  = (const float*)d_in[0];
  const int* mask = (const int*)d_in[1];
  const float* Wk = (const float*)d_in[2];   // NOTE: dict order — Wk before Wq
  const float* Wq = (const float*)d_in[3];
  const float* Wv = (const float*)d_in[4];
  const float* Wo = (const float*)d_in[5];
  float* out = (float*)d_out;

  // workspace: q(4MB) | k(4MB) | v(32MB) | ctx(32MB), all bf16
  unsigned short* qws   = (unsigned short*)d_ws;
  unsigned short* kws   = qws + 2097152;
  unsigned short* vws   = kws + 2097152;
  unsigned short* ctxws = vws + 16777216;

  hipMemsetAsync(d_out, 0, (size_t)out_size * sizeof(float), stream);  // for split-K atomics
  qkv_gemm<<<dim3(80, 16), 256, 0, stream>>>(h, Wq, Wk, Wv, qws, kws, vws);
  attn_kernel<<<2048, 256, 0, stream>>>(qws, kws, vws, mask, ctxws);
  out_gemm<<<dim3(16, 16), 256, 0, stream>>>(ctxws, Wo, out);
}

// Round 2
// 387.965 us; speedup vs baseline: 1.0791x; 1.0791x over previous
//
#include <hip/hip_runtime.h>

// CommAttention: B=256, NB=16, HID=512, NH=8, KD=64.
// R2: h pre-converted to bf16; qkv 256x64 tiles (W read once); out_gemm
// 256x64 tiles, 512 thr, split-K=4 with ws partials + reduce (no atomics);
// attn vectorized 16B loads.

typedef short s16x4 __attribute__((ext_vector_type(4)));
typedef short s16x8 __attribute__((ext_vector_type(8)));
typedef float f32x4 __attribute__((ext_vector_type(4)));

__device__ __forceinline__ unsigned short f2bf(float f) {
  unsigned int u = __builtin_bit_cast(unsigned int, f);
  u += 0x7fffu + ((u >> 16) & 1u);   // round-to-nearest-even
  return (unsigned short)(u >> 16);
}
__device__ __forceinline__ float bf2f(unsigned short s) {
  unsigned int u = ((unsigned int)s) << 16;
  return __builtin_bit_cast(float, u);
}

// ---------------------------------------------------------------------------
// Prologue: h (2M fp32) -> bf16. grid 2048 x 256.
// ---------------------------------------------------------------------------
__global__ __launch_bounds__(256) void cvt_h(const float* __restrict__ h,
                                             unsigned short* __restrict__ hb)
{
  int i = (blockIdx.x * 256 + threadIdx.x) * 4;
  float4 v = *reinterpret_cast<const float4*>(h + i);
  s16x4 st = { (short)f2bf(v.x), (short)f2bf(v.y), (short)f2bf(v.z), (short)f2bf(v.w) };
  *reinterpret_cast<s16x4*>(hb + i) = st;
}

// ---------------------------------------------------------------------------
// Phase A: grouped QKV projection. Tile 256x64, BK=32, 256 thr (4 waves,
// wave tile 64x64). grid (80, 16): 80 col-blocks over [Q 512|K 512|V 4096].
// W tiles each read exactly once.
// ---------------------------------------------------------------------------
__global__ __launch_bounds__(256) void qkv_gemm(
    const unsigned short* __restrict__ hb, const float* __restrict__ Wq,
    const float* __restrict__ Wk, const float* __restrict__ Wv,
    unsigned short* __restrict__ qo, unsigned short* __restrict__ ko,
    unsigned short* __restrict__ vo)
{
  const int g    = blockIdx.y;
  const int n0   = blockIdx.x * 64;     // in 5120-wide concat
  const int tid  = threadIdx.x;
  const int lane = tid & 63;
  const int wave = tid >> 6;            // 0..3
  const int wm   = wave * 64;

  const float* W; unsigned short* out; size_t obase; int oldc, wN, c0;
  if (n0 < 512)       { W = Wq + (size_t)g * 262144;  out = qo; obase = (size_t)g * 512;  oldc = 8192;  wN = 512;  c0 = n0; }
  else if (n0 < 1024) { W = Wk + (size_t)g * 262144;  out = ko; obase = (size_t)g * 512;  oldc = 8192;  wN = 512;  c0 = n0 - 512; }
  else                { W = Wv + (size_t)g * 2097152; out = vo; obase = (size_t)g * 4096; oldc = 65536; wN = 4096; c0 = n0 - 1024; }

  const unsigned short* A = hb + (size_t)g * 512;   // rows 0..255, stride 8192

  __shared__ unsigned short As[256][32];   // [m][k]
  __shared__ unsigned short Bs[64][36];    // [n][k] padded

  f32x4 acc[4][4];
  #pragma unroll
  for (int i = 0; i < 4; i++)
    #pragma unroll
    for (int j = 0; j < 4; j++) acc[i][j] = (f32x4){0.f, 0.f, 0.f, 0.f};

  const int fr = lane & 15, fq = lane >> 4;

  for (int k0 = 0; k0 < 512; k0 += 32) {
    __syncthreads();
    // A: 256x32 bf16, 16B loads, no conversion
    #pragma unroll
    for (int p = 0; p < 4; p++) {
      int idx = p * 256 + tid;
      int row = idx >> 2, kq = idx & 3;
      *reinterpret_cast<s16x8*>(&As[row][kq * 8]) =
          *reinterpret_cast<const s16x8*>(A + (size_t)row * 8192 + k0 + kq * 8);
    }
    // B: 64x32 via strided fp32 column-quad loads + cvt
    #pragma unroll
    for (int p = 0; p < 2; p++) {
      int idx = p * 256 + tid;
      int n = idx & 63, kc = idx >> 6;
      const float* wp = W + (size_t)(k0 + kc * 4) * wN + c0 + n;
      float w0 = wp[0], w1 = wp[wN], w2 = wp[2 * wN], w3 = wp[3 * wN];
      s16x4 st = { (short)f2bf(w0), (short)f2bf(w1), (short)f2bf(w2), (short)f2bf(w3) };
      *reinterpret_cast<s16x4*>(&Bs[n][kc * 4]) = st;
    }
    __syncthreads();
    s16x8 af[4], bfr[4];
    #pragma unroll
    for (int mi = 0; mi < 4; mi++)
      af[mi] = *reinterpret_cast<const s16x8*>(&As[wm + mi * 16 + fr][fq * 8]);
    #pragma unroll
    for (int ni = 0; ni < 4; ni++) {
      const s16x4* bp = reinterpret_cast<const s16x4*>(&Bs[ni * 16 + fr][fq * 8]);
      s16x4 lo = bp[0], hi = bp[1];
      bfr[ni] = __builtin_shufflevector(lo, hi, 0, 1, 2, 3, 4, 5, 6, 7);
    }
    #pragma unroll
    for (int mi = 0; mi < 4; mi++)
      #pragma unroll
      for (int ni = 0; ni < 4; ni++)
        acc[mi][ni] = __builtin_amdgcn_mfma_f32_16x16x32_bf16(af[mi], bfr[ni], acc[mi][ni], 0, 0, 0);
  }

  #pragma unroll
  for (int mi = 0; mi < 4; mi++)
    #pragma unroll
    for (int ni = 0; ni < 4; ni++)
      #pragma unroll
      for (int r = 0; r < 4; r++) {
        int row = wm + mi * 16 + fq * 4 + r;
        int col = c0 + ni * 16 + fr;
        out[obase + (size_t)row * oldc + col] = f2bf(acc[mi][ni][r]);
      }
}

// ---------------------------------------------------------------------------
// Phase B: per-(b,h) attention, vectorized. grid 2048, block 256.
// ---------------------------------------------------------------------------
__global__ __launch_bounds__(256) void attn_kernel(
    const unsigned short* __restrict__ q, const unsigned short* __restrict__ k,
    const unsigned short* __restrict__ v, const int* __restrict__ mask,
    unsigned short* __restrict__ ctx)
{
  const int b  = blockIdx.x >> 3;
  const int hh = blockIdx.x & 7;
  const int tid = threadIdx.x;

  __shared__ float qs[16][65];
  __shared__ float ks[16][65];
  __shared__ float sc[16][16];

  {
    int n = tid >> 4, d4 = (tid & 15) * 4;
    size_t gi = ((size_t)(b * 16 + n) << 9) + (hh << 6) + d4;
    ushort4 qv = *reinterpret_cast<const ushort4*>(q + gi);
    ushort4 kv = *reinterpret_cast<const ushort4*>(k + gi);
    qs[n][d4] = bf2f(qv.x); qs[n][d4+1] = bf2f(qv.y); qs[n][d4+2] = bf2f(qv.z); qs[n][d4+3] = bf2f(qv.w);
    ks[n][d4] = bf2f(kv.x); ks[n][d4+1] = bf2f(kv.y); ks[n][d4+2] = bf2f(kv.z); ks[n][d4+3] = bf2f(kv.w);
  }
  __syncthreads();
  {
    int qi = tid >> 4, ki = tid & 15;
    float s = 0.f;
    #pragma unroll
    for (int j = 0; j < 64; j++) s += qs[qi][j] * ks[ki][j];
    sc[qi][ki] = s * 0.125f;   // 1/sqrt(64)
  }
  __syncthreads();
  if (tid < 16) {
    float m = sc[tid][0];
    #pragma unroll
    for (int j = 1; j < 16; j++) m = fmaxf(m, sc[tid][j]);
    float ev[16], sum = 0.f;
    #pragma unroll
    for (int j = 0; j < 16; j++) { ev[j] = __expf(sc[tid][j] - m); sum += ev[j]; }
    float scale = (mask[b * 16 + tid] != 0) ? (1.f / sum) : 0.f;
    #pragma unroll
    for (int j = 0; j < 16; j++) sc[tid][j] = ev[j] * scale;
  }
  __syncthreads();
  // PV: thread owns 4 cols x 8 queries. v rows read as ushort4.
  {
    int col4  = (tid & 127) * 4;
    int qbase = (tid >> 7) * 8;
    float a0[8], a1[8], a2[8], a3[8];
    #pragma unroll
    for (int j = 0; j < 8; j++) { a0[j] = 0.f; a1[j] = 0.f; a2[j] = 0.f; a3[j] = 0.f; }
    #pragma unroll
    for (int kk = 0; kk < 16; kk++) {
      ushort4 vv = *reinterpret_cast<const ushort4*>(
          v + ((size_t)(b * 16 + kk) << 12) + (hh << 9) + col4);
      float v0 = bf2f(vv.x), v1 = bf2f(vv.y), v2 = bf2f(vv.z), v3 = bf2f(vv.w);
      #pragma unroll
      for (int j = 0; j < 8; j++) {
        float p = sc[qbase + j][kk];
        a0[j] += p * v0; a1[j] += p * v1; a2[j] += p * v2; a3[j] += p * v3;
      }
    }
    #pragma unroll
    for (int j = 0; j < 8; j++) {
      ushort4 st = { f2bf(a0[j]), f2bf(a1[j]), f2bf(a2[j]), f2bf(a3[j]) };
      *reinterpret_cast<ushort4*>(
          ctx + ((size_t)(b * 16 + qbase + j) << 12) + (hh << 9) + col4) = st;
    }
  }
}

// ---------------------------------------------------------------------------
// Phase C: partial[sk] = ctx @ Wo[g] over K-slice. Tile 256x64, 512 thr
// (8 waves, wave tile 64x32), split-K=4. grid (32, 16): bx = sk*8 + nb.
// ---------------------------------------------------------------------------
__global__ __launch_bounds__(512) void out_gemm(
    const unsigned short* __restrict__ ctxp, const float* __restrict__ Wo,
    float* __restrict__ partial)
{
  const int g    = blockIdx.y;
  const int bx   = blockIdx.x;
  const int sk   = bx >> 3;             // 0..3
  const int n0   = (bx & 7) * 64;       // 0..448
  const int tid  = threadIdx.x;
  const int lane = tid & 63;
  const int wave = tid >> 6;            // 0..7
  const int wm   = (wave >> 1) * 64;    // 4 positions
  const int wn   = (wave & 1) * 32;     // 2 positions

  const unsigned short* A = ctxp + (size_t)g * 4096;  // rows 0..255, stride 65536
  const float* W = Wo + (size_t)g * 2097152;          // 4096 x 512 fp32

  __shared__ unsigned short As[256][32];
  __shared__ unsigned short Bs[64][36];

  f32x4 acc[4][2];
  #pragma unroll
  for (int i = 0; i < 4; i++)
    #pragma unroll
    for (int j = 0; j < 2; j++) acc[i][j] = (f32x4){0.f, 0.f, 0.f, 0.f};

  const int fr = lane & 15, fq = lane >> 4;
  const int kend = sk * 1024 + 1024;

  for (int k0 = sk * 1024; k0 < kend; k0 += 32) {
    __syncthreads();
    // A: 256x32 bf16, 16B loads
    #pragma unroll
    for (int p = 0; p < 2; p++) {
      int idx = p * 512 + tid;
      int row = idx >> 2, kq = idx & 3;
      *reinterpret_cast<s16x8*>(&As[row][kq * 8]) =
          *reinterpret_cast<const s16x8*>(A + (size_t)row * 65536 + k0 + kq * 8);
    }
    // B: 64x32 fp32 column-quads + cvt (one per thread)
    {
      int n = tid & 63, kc = tid >> 6;
      const float* wp = W + (size_t)(k0 + kc * 4) * 512 + n0 + n;
      float w0 = wp[0], w1 = wp[512], w2 = wp[1024], w3 = wp[1536];
      s16x4 st = { (short)f2bf(w0), (short)f2bf(w1), (short)f2bf(w2), (short)f2bf(w3) };
      *reinterpret_cast<s16x4*>(&Bs[n][kc * 4]) = st;
    }
    __syncthreads();
    s16x8 af[4], bfr[2];
    #pragma unroll
    for (int mi = 0; mi < 4; mi++)
      af[mi] = *reinterpret_cast<const s16x8*>(&As[wm + mi * 16 + fr][fq * 8]);
    #pragma unroll
    for (int ni = 0; ni < 2; ni++) {
      const s16x4* bp = reinterpret_cast<const s16x4*>(&Bs[wn + ni * 16 + fr][fq * 8]);
      s16x4 lo = bp[0], hi = bp[1];
      bfr[ni] = __builtin_shufflevector(lo, hi, 0, 1, 2, 3, 4, 5, 6, 7);
    }
    #pragma unroll
    for (int mi = 0; mi < 4; mi++)
      #pragma unroll
      for (int ni = 0; ni < 2; ni++)
        acc[mi][ni] = __builtin_amdgcn_mfma_f32_16x16x32_bf16(af[mi], bfr[ni], acc[mi][ni], 0, 0, 0);
  }

  float* pg = partial + (size_t)sk * 2097152 + (size_t)g * 512;
  #pragma unroll
  for (int mi = 0; mi < 4; mi++)
    #pragma unroll
    for (int ni = 0; ni < 2; ni++)
      #pragma unroll
      for (int r = 0; r < 4; r++) {
        int row = wm + mi * 16 + fq * 4 + r;
        int col = n0 + wn + ni * 16 + fr;
        pg[(size_t)row * 8192 + col] = acc[mi][ni][r];
      }
}

// ---------------------------------------------------------------------------
// Epilogue: out = sum of 4 split-K partials. grid 2048 x 256.
// ---------------------------------------------------------------------------
__global__ __launch_bounds__(256) void reduce4(const float* __restrict__ part,
                                               float* __restrict__ out)
{
  int i = (blockIdx.x * 256 + threadIdx.x) * 4;
  float4 a = *reinterpret_cast<const float4*>(part + i);
  float4 b = *reinterpret_cast<const float4*>(part + 2097152 + i);
  float4 c = *reinterpret_cast<const float4*>(part + 4194304 + i);
  float4 d = *reinterpret_cast<const float4*>(part + 6291456 + i);
  float4 s = { a.x + b.x + c.x + d.x, a.y + b.y + c.y + d.y,
               a.z + b.z + c.z + d.z, a.w + b.w + c.w + d.w };
  *reinterpret_cast<float4*>(out + i) = s;
}

// ---------------------------------------------------------------------------
extern "C" void kernel_launch(void* const* d_in, const int* in_sizes, int n_in,
                              void* d_out, int out_size, void* d_ws, size_t ws_size,
                              hipStream_t stream) {
  const float* h  = (const float*)d_in[0];
  const int* mask = (const int*)d_in[1];
  const float* Wk = (const float*)d_in[2];   // dict order: Wk before Wq
  const float* Wq = (const float*)d_in[3];
  const float* Wv = (const float*)d_in[4];
  const float* Wo = (const float*)d_in[5];
  float* out = (float*)d_out;

  // ws layout: q(4MB) | k(4MB) | v(33.5MB) | ctx(33.5MB)
  // hb (4MB)  aliases ctx region   (dead once attn writes ctx)
  // partials (33.5MB) alias q/k/v  (dead once out_gemm runs)
  unsigned short* qws   = (unsigned short*)d_ws;
  unsigned short* kws   = qws + 2097152;
  unsigned short* vws   = kws + 2097152;
  unsigned short* ctxws = vws + 16777216;
  unsigned short* hb    = ctxws;             // alias: used before attn only
  float* part           = (float*)d_ws;      // alias: used after attn only

  cvt_h<<<2048, 256, 0, stream>>>(h, hb);
  qkv_gemm<<<dim3(80, 16), 256, 0, stream>>>(hb, Wq, Wk, Wv, qws, kws, vws);
  attn_kernel<<<2048, 256, 0, stream>>>(qws, kws, vws, mask, ctxws);
  out_gemm<<<dim3(32, 16), 512, 0, stream>>>(ctxws, Wo, part);
  reduce4<<<2048, 256, 0, stream>>>(part, out);
}